// Round 1
// baseline (1435.179 us; speedup 1.0000x reference)
//
#include <hip/hip_runtime.h>

#define HD 64
#define FC 16
#define FEMB 8

// ---- degree count: integer atomics (deterministic) ----
__global__ void k_deg_count(const int* __restrict__ dst, int* __restrict__ deg, int E) {
    int stride = gridDim.x * blockDim.x;
    for (int i = blockIdx.x * blockDim.x + threadIdx.x; i < E; i += stride)
        atomicAdd(&deg[dst[i]], 1);
}

__global__ void k_deg_isq(const int* __restrict__ deg, float* __restrict__ disq, int n) {
    int stride = gridDim.x * blockDim.x;
    for (int i = blockIdx.x * blockDim.x + threadIdx.x; i < n; i += stride)
        disq[i] = 1.0f / sqrtf(1.0f + (float)deg[i]);
}

// ---- input layer: x = relu(concat(x_cont, emb[ft]) @ W_in + b_in) ----
// one wave per node, lane = output column
__global__ void k_input(const float* __restrict__ xc, const int* __restrict__ ft,
                        const float* __restrict__ emb, const float* __restrict__ Win,
                        const float* __restrict__ bin, float* __restrict__ x, int n) {
    int lane = threadIdx.x & 63;
    int wid  = (blockIdx.x * blockDim.x + threadIdx.x) >> 6;
    int nw   = (gridDim.x * blockDim.x) >> 6;
    for (int node = wid; node < n; node += nw) {
        float acc = bin[lane];
        const float* xr = xc + (size_t)node * FC;
#pragma unroll
        for (int k = 0; k < FC; k++)
            acc = fmaf(xr[k], Win[k * HD + lane], acc);
        int t = ft[node];
        const float* er = emb + (size_t)t * FEMB;
#pragma unroll
        for (int k = 0; k < FEMB; k++)
            acc = fmaf(er[k], Win[(FC + k) * HD + lane], acc);
        x[(size_t)node * HD + lane] = fmaxf(acc, 0.0f);
    }
}

// ---- h = x @ W  (64x64), wave per node, lane = output column ----
__global__ void k_matmul(const float* __restrict__ x, const float* __restrict__ W,
                         float* __restrict__ h, int n) {
    int lane = threadIdx.x & 63;
    int wid  = (blockIdx.x * blockDim.x + threadIdx.x) >> 6;
    int nw   = (gridDim.x * blockDim.x) >> 6;
    for (int node = wid; node < n; node += nw) {
        const float4* xr = (const float4*)(x + (size_t)node * HD);
        float acc = 0.0f;
#pragma unroll
        for (int k4 = 0; k4 < HD / 4; k4++) {
            float4 v = xr[k4];
            acc = fmaf(v.x, W[(k4 * 4 + 0) * HD + lane], acc);
            acc = fmaf(v.y, W[(k4 * 4 + 1) * HD + lane], acc);
            acc = fmaf(v.z, W[(k4 * 4 + 2) * HD + lane], acc);
            acc = fmaf(v.w, W[(k4 * 4 + 3) * HD + lane], acc);
        }
        h[(size_t)node * HD + lane] = acc;
    }
}

// ---- agg := deg_isq^2 * h  (self-loop term; also serves as the zero-init) ----
__global__ void k_selfinit(const float* __restrict__ h, const float* __restrict__ disq,
                           float* __restrict__ agg, int n64_4) {
    int stride = gridDim.x * blockDim.x;
    for (int i = blockIdx.x * blockDim.x + threadIdx.x; i < n64_4; i += stride) {
        int node = i >> 4;  // 16 float4 per node row
        float di = disq[node];
        float w = di * di;
        float4 v = ((const float4*)h)[i];
        float4 o;
        o.x = v.x * w; o.y = v.y * w; o.z = v.z * w; o.w = v.w * w;
        ((float4*)agg)[i] = o;
    }
}

// ---- edge scatter: agg[dst] += disq[src]*disq[dst] * h[src] ----
// one wave per edge, lane = feature
__global__ void k_edge(const int* __restrict__ src, const int* __restrict__ dst,
                       const float* __restrict__ disq, const float* __restrict__ h,
                       float* __restrict__ agg, int E) {
    int lane = threadIdx.x & 63;
    int wid  = (blockIdx.x * blockDim.x + threadIdx.x) >> 6;
    int nw   = (gridDim.x * blockDim.x) >> 6;
    for (int e = wid; e < E; e += nw) {
        int s = src[e], d = dst[e];
        float nm = disq[s] * disq[d];
        atomicAdd(&agg[(size_t)d * HD + lane], nm * h[(size_t)s * HD + lane]);
    }
}

// ---- x = relu(x + b) in place ----
__global__ void k_bias_relu(float* __restrict__ x, const float* __restrict__ b, int n64_4) {
    int stride = gridDim.x * blockDim.x;
    for (int i = blockIdx.x * blockDim.x + threadIdx.x; i < n64_4; i += stride) {
        float4 v = ((float4*)x)[i];
        float4 bb = ((const float4*)b)[i & 15];
        v.x = fmaxf(v.x + bb.x, 0.0f);
        v.y = fmaxf(v.y + bb.y, 0.0f);
        v.z = fmaxf(v.z + bb.z, 0.0f);
        v.w = fmaxf(v.w + bb.w, 0.0f);
        ((float4*)x)[i] = v;
    }
}

// ---- head: out = relu(x @ W_o1 + b_o1) @ W_o2 + b_o2 ----
__global__ void k_head(const float* __restrict__ x, const float* __restrict__ W1,
                       const float* __restrict__ b1, const float* __restrict__ W2,
                       const float* __restrict__ b2, float* __restrict__ out, int n) {
    int lane = threadIdx.x & 63;
    int wid  = (blockIdx.x * blockDim.x + threadIdx.x) >> 6;
    int nw   = (gridDim.x * blockDim.x) >> 6;
    float w2  = W2[lane];
    float b2v = b2[0];
    for (int node = wid; node < n; node += nw) {
        const float4* xr = (const float4*)(x + (size_t)node * HD);
        float acc = b1[lane];
#pragma unroll
        for (int k4 = 0; k4 < HD / 4; k4++) {
            float4 v = xr[k4];
            acc = fmaf(v.x, W1[(k4 * 4 + 0) * HD + lane], acc);
            acc = fmaf(v.y, W1[(k4 * 4 + 1) * HD + lane], acc);
            acc = fmaf(v.z, W1[(k4 * 4 + 2) * HD + lane], acc);
            acc = fmaf(v.w, W1[(k4 * 4 + 3) * HD + lane], acc);
        }
        float pp = fmaxf(acc, 0.0f) * w2;
#pragma unroll
        for (int off = 32; off > 0; off >>= 1)
            pp += __shfl_xor(pp, off);
        if (lane == 0) out[node] = pp + b2v;
    }
}

extern "C" void kernel_launch(void* const* d_in, const int* in_sizes, int n_in,
                              void* d_out, int out_size, void* d_ws, size_t ws_size,
                              hipStream_t stream) {
    const float* x_cont = (const float*)d_in[0];
    const int*   ftyp   = (const int*)d_in[1];
    const int*   eidx   = (const int*)d_in[2];
    const float* emb    = (const float*)d_in[3];
    const float* W_in   = (const float*)d_in[4];
    const float* b_in   = (const float*)d_in[5];
    const float* W_g    = (const float*)d_in[6];
    const float* b_g    = (const float*)d_in[7];
    const float* W_o1   = (const float*)d_in[8];
    const float* b_o1   = (const float*)d_in[9];
    const float* W_o2   = (const float*)d_in[10];
    const float* b_o2   = (const float*)d_in[11];
    float* out = (float*)d_out;

    const int n = in_sizes[1];       // N nodes (func_type length)
    const int E = in_sizes[2] / 2;   // edge count
    const int* src = eidx;
    const int* dst = eidx + E;

    char* p = (char*)d_ws;
    auto alloc = [&](size_t bytes) {
        char* r = p;
        p += (bytes + 255) & ~(size_t)255;
        return r;
    };
    int*   deg  = (int*)  alloc((size_t)n * 4);
    float* disq = (float*)alloc((size_t)n * 4);
    float* xb   = (float*)alloc((size_t)n * HD * 4);
    float* hb   = (float*)alloc((size_t)n * HD * 4);

    hipMemsetAsync(deg, 0, (size_t)n * 4, stream);

    dim3 blk(256);
    const int nb_e = 2048;  // edge-parallel kernels
    const int nb_n = 1024;  // node-per-wave kernels (4096 waves)
    const int nb_v = 2048;  // elementwise float4 kernels
    const int n64_4 = n * HD / 4;

    k_deg_count<<<nb_e, blk, 0, stream>>>(dst, deg, E);
    k_deg_isq<<<512, blk, 0, stream>>>(deg, disq, n);
    k_input<<<nb_n, blk, 0, stream>>>(x_cont, ftyp, emb, W_in, b_in, xb, n);

    for (int L = 0; L < 3; L++) {
        k_matmul<<<nb_n, blk, 0, stream>>>(xb, W_g + (size_t)L * HD * HD, hb, n);
        k_selfinit<<<nb_v, blk, 0, stream>>>(hb, disq, xb, n64_4);
        k_edge<<<nb_e, blk, 0, stream>>>(src, dst, disq, hb, xb, E);
        k_bias_relu<<<nb_v, blk, 0, stream>>>(xb, b_g + (size_t)L * HD, n64_4);
    }

    k_head<<<nb_n, blk, 0, stream>>>(xb, W_o1, b_o1, W_o2, b_o2, out, n);
}

// Round 2
// 826.995 us; speedup vs baseline: 1.7354x; 1.7354x over previous
//
#include <hip/hip_runtime.h>

#define HD 64
#define FC 16
#define FEMB 8

// ---- degree count: integer atomics ----
__global__ void k_deg_count(const int* __restrict__ dst, int* __restrict__ deg, int E) {
    int stride = gridDim.x * blockDim.x;
    for (int i = blockIdx.x * blockDim.x + threadIdx.x; i < E; i += stride)
        atomicAdd(&deg[dst[i]], 1);
}

// ---- scan phase 1: per-block exclusive scan of deg; also compute disq ----
__global__ void k_scan1(const int* __restrict__ deg, int* __restrict__ row_part,
                        int* __restrict__ bsum, float* __restrict__ disq, int n) {
    __shared__ int s[256];
    int t = threadIdx.x;
    int i = blockIdx.x * 256 + t;
    int v = (i < n) ? deg[i] : 0;
    if (i < n) disq[i] = rsqrtf(1.0f + (float)v);
    s[t] = v;
    __syncthreads();
    for (int off = 1; off < 256; off <<= 1) {
        int a = (t >= off) ? s[t - off] : 0;
        __syncthreads();
        s[t] += a;
        __syncthreads();
    }
    if (i < n) row_part[i] = s[t] - v;       // exclusive within block
    if (t == 255) bsum[blockIdx.x] = s[255]; // block total
}

// ---- scan phase 2: exclusive scan of block sums (single block, nb <= 1024) ----
__global__ void k_scan2(int* __restrict__ bsum, int nb) {
    __shared__ int s[1024];
    int t = threadIdx.x;
    int v = (t < nb) ? bsum[t] : 0;
    s[t] = v;
    __syncthreads();
    for (int off = 1; off < 1024; off <<= 1) {
        int a = (t >= off) ? s[t - off] : 0;
        __syncthreads();
        s[t] += a;
        __syncthreads();
    }
    if (t < nb) bsum[t] = s[t] - v;
}

// ---- scan phase 3: add block offsets; init cursor copy ----
__global__ void k_scan3(int* __restrict__ row_part, const int* __restrict__ bsum,
                        int* __restrict__ cursor, int n) {
    int stride = gridDim.x * blockDim.x;
    for (int i = blockIdx.x * blockDim.x + threadIdx.x; i < n; i += stride) {
        int rs = row_part[i] + bsum[i >> 8];
        row_part[i] = rs;
        cursor[i] = rs;
    }
}

// ---- scatter edges into CSR slots: {src, disq[src]} packed as int2 ----
__global__ void k_scatter(const int* __restrict__ src, const int* __restrict__ dst,
                          const float* __restrict__ disq, int* __restrict__ cursor,
                          int2* __restrict__ csr, int E) {
    int stride = gridDim.x * blockDim.x;
    for (int e = blockIdx.x * blockDim.x + threadIdx.x; e < E; e += stride) {
        int s = src[e], d = dst[e];
        int pos = atomicAdd(&cursor[d], 1);
        csr[pos] = make_int2(s, __float_as_int(disq[s]));
    }
}

// ---- input layer: x = relu(concat(x_cont, emb[ft]) @ W_in + b_in) ----
__global__ void k_input(const float* __restrict__ xc, const int* __restrict__ ft,
                        const float* __restrict__ emb, const float* __restrict__ Win,
                        const float* __restrict__ bin, float* __restrict__ x, int n) {
    int lane = threadIdx.x & 63;
    int wid  = (blockIdx.x * blockDim.x + threadIdx.x) >> 6;
    int nw   = (gridDim.x * blockDim.x) >> 6;
    for (int node = wid; node < n; node += nw) {
        float acc = bin[lane];
        const float* xr = xc + (size_t)node * FC;
#pragma unroll
        for (int k = 0; k < FC; k++)
            acc = fmaf(xr[k], Win[k * HD + lane], acc);
        int t = ft[node];
        const float* er = emb + (size_t)t * FEMB;
#pragma unroll
        for (int k = 0; k < FEMB; k++)
            acc = fmaf(er[k], Win[(FC + k) * HD + lane], acc);
        x[(size_t)node * HD + lane] = fmaxf(acc, 0.0f);
    }
}

// ---- fused GCN layer: aggregate x (CSR gather), then apply W via in-wave
//      LDS broadcast + per-lane W column in registers; bias + relu ----
__global__ void k_layer(const float* __restrict__ x, const int2* __restrict__ csr,
                        const int* __restrict__ rs, const int* __restrict__ deg,
                        const float* __restrict__ disq, const float* __restrict__ W,
                        const float* __restrict__ b, float* __restrict__ xo, int n) {
    __shared__ float rows[4][HD];  // one row per wave (256-thread block)
    int lane = threadIdx.x & 63;
    int w    = threadIdx.x >> 6;
    int wid  = (blockIdx.x * blockDim.x + threadIdx.x) >> 6;
    int nw   = (gridDim.x * blockDim.x) >> 6;

    // preload this lane's W column (64 VGPRs, static indexing via unroll)
    float wreg[HD];
#pragma unroll
    for (int k = 0; k < HD; k++) wreg[k] = W[k * HD + lane];
    float bl = b[lane];

    for (int node = wid; node < n; node += nw) {
        int start = rs[node];
        int cnt   = deg[node];
        float di  = disq[node];
        float acc = 0.0f;
        for (int j = start; j < start + cnt; j++) {
            int2 e = csr[j];                       // wave-uniform 8B load
            acc = fmaf(__int_as_float(e.y), x[(size_t)e.x * HD + lane], acc);
        }
        float aggv = fmaf(di, acc, di * di * x[(size_t)node * HD + lane]);
        rows[w][lane] = aggv;                      // in-wave broadcast via LDS
        float o = bl;
#pragma unroll
        for (int k = 0; k < HD; k++)
            o = fmaf(rows[w][k], wreg[k], o);
        xo[(size_t)node * HD + lane] = fmaxf(o, 0.0f);
    }
}

// ---- head: out = relu(x @ W_o1 + b_o1) @ W_o2 + b_o2 ----
__global__ void k_head(const float* __restrict__ x, const float* __restrict__ W1,
                       const float* __restrict__ b1, const float* __restrict__ W2,
                       const float* __restrict__ b2, float* __restrict__ out, int n) {
    int lane = threadIdx.x & 63;
    int wid  = (blockIdx.x * blockDim.x + threadIdx.x) >> 6;
    int nw   = (gridDim.x * blockDim.x) >> 6;
    float w2  = W2[lane];
    float b2v = b2[0];
    for (int node = wid; node < n; node += nw) {
        const float4* xr = (const float4*)(x + (size_t)node * HD);
        float acc = b1[lane];
#pragma unroll
        for (int k4 = 0; k4 < HD / 4; k4++) {
            float4 v = xr[k4];
            acc = fmaf(v.x, W1[(k4 * 4 + 0) * HD + lane], acc);
            acc = fmaf(v.y, W1[(k4 * 4 + 1) * HD + lane], acc);
            acc = fmaf(v.z, W1[(k4 * 4 + 2) * HD + lane], acc);
            acc = fmaf(v.w, W1[(k4 * 4 + 3) * HD + lane], acc);
        }
        float pp = fmaxf(acc, 0.0f) * w2;
#pragma unroll
        for (int off = 32; off > 0; off >>= 1)
            pp += __shfl_xor(pp, off);
        if (lane == 0) out[node] = pp + b2v;
    }
}

extern "C" void kernel_launch(void* const* d_in, const int* in_sizes, int n_in,
                              void* d_out, int out_size, void* d_ws, size_t ws_size,
                              hipStream_t stream) {
    const float* x_cont = (const float*)d_in[0];
    const int*   ftyp   = (const int*)d_in[1];
    const int*   eidx   = (const int*)d_in[2];
    const float* emb    = (const float*)d_in[3];
    const float* W_in   = (const float*)d_in[4];
    const float* b_in   = (const float*)d_in[5];
    const float* W_g    = (const float*)d_in[6];
    const float* b_g    = (const float*)d_in[7];
    const float* W_o1   = (const float*)d_in[8];
    const float* b_o1   = (const float*)d_in[9];
    const float* W_o2   = (const float*)d_in[10];
    const float* b_o2   = (const float*)d_in[11];
    float* out = (float*)d_out;

    const int n = in_sizes[1];       // N nodes
    const int E = in_sizes[2] / 2;   // edges
    const int* src = eidx;
    const int* dst = eidx + E;

    char* p = (char*)d_ws;
    auto alloc = [&](size_t bytes) {
        char* r = p;
        p += (bytes + 255) & ~(size_t)255;
        return r;
    };
    int*   deg    = (int*)  alloc((size_t)n * 4);
    float* disq   = (float*)alloc((size_t)n * 4);
    int*   rowst  = (int*)  alloc((size_t)n * 4);
    int*   cursor = (int*)  alloc((size_t)n * 4);
    int*   bsum   = (int*)  alloc(4096);
    int2*  csr    = (int2*) alloc((size_t)E * 8);
    float* xb     = (float*)alloc((size_t)n * HD * 4);
    float* xo     = (float*)alloc((size_t)n * HD * 4);

    hipMemsetAsync(deg, 0, (size_t)n * 4, stream);

    dim3 blk(256);
    const int nb1 = (n + 255) / 256;  // scan blocks (391 for n=100k, <=1024)
    const int nb_e = 2048;
    const int nb_n = 1024;

    k_deg_count<<<nb_e, blk, 0, stream>>>(dst, deg, E);
    k_scan1<<<nb1, blk, 0, stream>>>(deg, rowst, bsum, disq, n);
    k_scan2<<<1, 1024, 0, stream>>>(bsum, nb1);
    k_scan3<<<512, blk, 0, stream>>>(rowst, bsum, cursor, n);
    k_scatter<<<nb_e, blk, 0, stream>>>(src, dst, disq, cursor, csr, E);
    k_input<<<nb_n, blk, 0, stream>>>(x_cont, ftyp, emb, W_in, b_in, xb, n);

    float* a = xb;
    float* bpp = xo;
    for (int L = 0; L < 3; L++) {
        k_layer<<<nb_n, blk, 0, stream>>>(a, csr, rowst, deg, disq,
                                          W_g + (size_t)L * HD * HD,
                                          b_g + (size_t)L * HD, bpp, n);
        float* t = a; a = bpp; bpp = t;
    }

    k_head<<<nb_n, blk, 0, stream>>>(a, W_o1, b_o1, W_o2, b_o2, out, n);
}